// Round 15
// baseline (233.153 us; speedup 1.0000x reference)
//
#include <hip/hip_runtime.h>
#include <hip/hip_bf16.h>
#include <math.h>

#define NG 128
#define CHUNKB 4096
#define NBIN 512     // dst buckets of 256 nodes; >= ceil(N/256)
#define EWIN 256     // per-wave LDS edge window (16 nodes, mean 160, 5-sigma ~225)

typedef __attribute__((ext_vector_type(8))) short short8;
typedef __attribute__((ext_vector_type(4))) float float4v;

static __device__ __forceinline__ float bf2f(__hip_bfloat16 v) { return __bfloat162float(v); }

// ---------- per-chunk bucket histogram (LDS only, no global atomics) ----------
__global__ void k_bin_hist(const int* __restrict__ dst, int* __restrict__ hist,
                           int e, int nb) {
    __shared__ int h[NBIN];
    for (int i = threadIdx.x; i < NBIN; i += 256) h[i] = 0;
    __syncthreads();
    int base = blockIdx.x * CHUNKB;
    int lim = e - base; if (lim > CHUNKB) lim = CHUNKB;
    for (int k = threadIdx.x; k < lim; k += 256)
        atomicAdd(&h[dst[base + k] >> 8], 1);
    __syncthreads();
    for (int b = threadIdx.x; b < NBIN; b += 256) hist[b * nb + blockIdx.x] = h[b];
}

// ---------- generic exclusive scan (512-thread blocks) ----------
__global__ void __launch_bounds__(512) genscan1(int* __restrict__ a, int* __restrict__ bsums, int n) {
    __shared__ int s[512];
    int tid = threadIdx.x;
    int i = blockIdx.x * 512 + tid;
    int v = (i < n) ? a[i] : 0;
    s[tid] = v;
    __syncthreads();
    for (int d = 1; d < 512; d <<= 1) {
        int t = (tid >= d) ? s[tid - d] : 0;
        __syncthreads();
        s[tid] += t;
        __syncthreads();
    }
    if (i < n) a[i] = s[tid] - v;   // exclusive, in place
    if (tid == 511) bsums[blockIdx.x] = s[511];
}

__global__ void __launch_bounds__(512) genscan2(int* __restrict__ bsums, int nb) {
    __shared__ int s[512];
    int tid = threadIdx.x;
    int v = (tid < nb) ? bsums[tid] : 0;
    s[tid] = v;
    __syncthreads();
    for (int d = 1; d < 512; d <<= 1) {
        int t = (tid >= d) ? s[tid - d] : 0;
        __syncthreads();
        s[tid] += t;
        __syncthreads();
    }
    if (tid < nb) bsums[tid] = s[tid] - v;
}
// genscan3 fused into consumers: offset(i) = hist[i] + bsums[i >> 9]

// ---------- LDS-staged bucket scatter (exact offsets, clustered writes) ----------
__global__ void k_bin_scatter(const int* __restrict__ srcs, const int* __restrict__ dsts,
                              const int* __restrict__ offsets, const int* __restrict__ bsums,
                              int2* __restrict__ outbuf, int e, int nb) {
    __shared__ int hcnt[NBIN];     // counts -> cursor
    __shared__ int lstart[NBIN];   // local start -> delta
    __shared__ int ss[256];
    __shared__ int2 stage[CHUNKB];
    int tid = threadIdx.x, blk = blockIdx.x, base = blk * CHUNKB;
    int lim = e - base; if (lim > CHUNKB) lim = CHUNKB;
    for (int i = tid; i < NBIN; i += 256) hcnt[i] = 0;
    __syncthreads();
    for (int k = tid; k < lim; k += 256)
        atomicAdd(&hcnt[dsts[base + k] >> 8], 1);
    __syncthreads();
    int c0 = hcnt[2 * tid], c1 = hcnt[2 * tid + 1];
    int sum = c0 + c1;
    ss[tid] = sum;
    __syncthreads();
    for (int d = 1; d < 256; d <<= 1) {
        int t = (tid >= d) ? ss[tid - d] : 0;
        __syncthreads();
        ss[tid] += t;
        __syncthreads();
    }
    int excl = ss[tid] - sum;
    lstart[2 * tid] = excl;
    lstart[2 * tid + 1] = excl + c0;
    __syncthreads();
    hcnt[2 * tid] = excl;          // cursors
    hcnt[2 * tid + 1] = excl + c0;
    __syncthreads();
    for (int k = tid; k < lim; k += 256) {
        int2 ed = make_int2(srcs[base + k], dsts[base + k]);
        int p = atomicAdd(&hcnt[ed.y >> 8], 1);
        stage[p] = ed;
    }
    __syncthreads();
    for (int i = tid; i < NBIN; i += 256) {
        int gi = i * nb + blk;
        lstart[i] = offsets[gi] + bsums[gi >> 9] - lstart[i];
    }
    __syncthreads();
    for (int p = tid; p < lim; p += 256) {
        int2 ed = stage[p];
        outbuf[lstart[ed.y >> 8] + p] = ed;
    }
}

// ---------- block per bucket: per-node degree (LDS), row_ptr, dinv ----------
__global__ void k_csrA(const int2* __restrict__ ebuck, const int* __restrict__ offsets,
                       const int* __restrict__ bsums, int* __restrict__ row_ptr,
                       float* __restrict__ dinv, int n, int nb, int nbuk, int e_total) {
    __shared__ int lcnt[256];
    __shared__ int ssc[256];
    int b = blockIdx.x, tid = threadIdx.x, n0 = b << 8;
    lcnt[tid] = 0;
    __syncthreads();
    int i0 = b * nb, i1 = (b + 1) * nb;
    int e0 = offsets[i0] + bsums[i0 >> 9];
    int e1 = offsets[i1] + bsums[i1 >> 9];
    for (int i = e0 + tid; i < e1; i += 256)
        atomicAdd(&lcnt[ebuck[i].y - n0], 1);
    __syncthreads();
    int v = lcnt[tid];
    ssc[tid] = v;
    __syncthreads();
    for (int d = 1; d < 256; d <<= 1) {
        int t = (tid >= d) ? ssc[tid - d] : 0;
        __syncthreads();
        ssc[tid] += t;
        __syncthreads();
    }
    int node = n0 + tid;
    if (node < n) {
        row_ptr[node] = e0 + ssc[tid] - v;   // exclusive
        dinv[node] = rsqrtf((float)v + 1.0f);
        if (node == n - 1) row_ptr[n] = e_total;
    }
}

// ---------- block per bucket: place edges at exact CSR pos, precompute w ----------
__global__ void k_csrB(const int2* __restrict__ ebuck, const int* __restrict__ offsets,
                       const int* __restrict__ bsums, const int* __restrict__ row_ptr,
                       const float* __restrict__ dinv, int2* __restrict__ csr, int nb) {
    __shared__ int lcur[256];
    int b = blockIdx.x, tid = threadIdx.x, n0 = b << 8;
    lcur[tid] = 0;
    __syncthreads();
    int i0 = b * nb, i1 = (b + 1) * nb;
    int e0 = offsets[i0] + bsums[i0 >> 9];
    int e1 = offsets[i1] + bsums[i1 >> 9];
    for (int i = e0 + tid; i < e1; i += 256) {
        int2 ed = ebuck[i];
        int r = atomicAdd(&lcur[ed.y - n0], 1);
        int pos = row_ptr[ed.y] + r;
        float w = dinv[ed.x] * dinv[ed.y];
        csr[pos] = make_int2(ed.x, __float_as_int(w));
    }
}

// ---------- layer 1 fused: pull on x (2 feats) + lin1 + relu -> h1 bf16 ----------
__global__ void k_layer1(const int* __restrict__ row_ptr, const int2* __restrict__ edges,
                         const float* __restrict__ x, const float* __restrict__ dinv,
                         const float* __restrict__ W1, const float* __restrict__ b1,
                         __hip_bfloat16* __restrict__ h, int n) {
    __shared__ float w1s[128];
    __shared__ float b1s[64];
    if (threadIdx.x < 128) w1s[threadIdx.x] = W1[threadIdx.x];
    if (threadIdx.x < 64) b1s[threadIdx.x] = b1[threadIdx.x];
    __syncthreads();
    int i = blockIdx.x * blockDim.x + threadIdx.x;
    if (i >= n) return;
    const float2* x2 = (const float2*)x;
    float dd = dinv[i], d2 = dd * dd;
    float2 xi = x2[i];
    float a0 = d2 * xi.x, a1 = d2 * xi.y;
    int lo = row_ptr[i], hi = row_ptr[i + 1];
    int k = lo;
    for (; k + 4 <= hi; k += 4) {
        int2 e0 = edges[k], e1 = edges[k + 1], e2 = edges[k + 2], e3 = edges[k + 3];
        float2 v0 = x2[e0.x], v1 = x2[e1.x], v2 = x2[e2.x], v3 = x2[e3.x];
        a0 += __int_as_float(e0.y) * v0.x; a1 += __int_as_float(e0.y) * v0.y;
        a0 += __int_as_float(e1.y) * v1.x; a1 += __int_as_float(e1.y) * v1.y;
        a0 += __int_as_float(e2.y) * v2.x; a1 += __int_as_float(e2.y) * v2.y;
        a0 += __int_as_float(e3.y) * v3.x; a1 += __int_as_float(e3.y) * v3.y;
    }
    for (; k < hi; k++) {
        int2 e = edges[k];
        float2 v = x2[e.x];
        a0 += __int_as_float(e.y) * v.x;
        a1 += __int_as_float(e.y) * v.y;
    }
    short8* hv = reinterpret_cast<short8*>(h + (size_t)i * 64);
    #pragma unroll
    for (int g = 0; g < 8; g++) {
        short8 pack;
        #pragma unroll
        for (int j = 0; j < 8; j++) {
            int col = g * 8 + j;
            float v = fmaxf(a0 * w1s[col] + a1 * w1s[64 + col] + b1s[col], 0.0f);
            __hip_bfloat16 bv = __float2bfloat16(v);
            pack[j] = *reinterpret_cast<short*>(&bv);
        }
        hv[g] = pack;
    }
}

// ---------- per-node gather core (edges from LDS window or global) ----------
template <bool FAST>
static __device__ __forceinline__ void agg_node(int lo, int hi, int half, int col,
        const int2* __restrict__ gE, const int2* EW, int wave_lo,
        const uint* __restrict__ hinu, float& ax, float& ay) {
    for (int k = lo; k < hi; k += 16) {
        int ss[8]; float ww[8];
        #pragma unroll
        for (int j = 0; j < 8; j++) {
            int idx = k + 2 * j + half;
            int cidx = idx < hi ? idx : lo;      // clamped, always valid
            int2 ee = FAST ? EW[cidx - wave_lo] : gE[cidx];
            ss[j] = ee.x;
            ww[j] = idx < hi ? __int_as_float(ee.y) : 0.0f;
        }
        uint vv[8];
        #pragma unroll
        for (int j = 0; j < 8; j++) vv[j] = hinu[(size_t)ss[j] * 32 + col];
        #pragma unroll
        for (int j = 0; j < 8; j++) {
            ax += ww[j] * __int_as_float(vv[j] << 16);
            ay += ww[j] * __int_as_float(vv[j] & 0xffff0000u);
        }
    }
}

// ---------- fused agg + MFMA linear (+ optional fused mean-pool) ----------
// TWO independent waves per block (128 threads): beats the ~16 workgroup-slots/CU
// cap that limited 1-wave blocks to 36% occupancy (R14). 16 blocks/CU x 2 waves
// = 32 waves/CU. Waves stay fully independent (private LDS, no barrier).
template <int RELU, int POOL>
__global__ void __launch_bounds__(128, 8) k_aggLin(const int* __restrict__ row_ptr,
                                                   const int2* __restrict__ edges,
                                                   const __hip_bfloat16* __restrict__ hin,
                                                   const float* __restrict__ dinv,
                                                   const __hip_bfloat16* __restrict__ Wf,
                                                   const float* __restrict__ b,
                                                   __hip_bfloat16* __restrict__ hout,
                                                   const int* __restrict__ batch,
                                                   float* __restrict__ sums, int n) {
    __shared__ __attribute__((aligned(16))) __hip_bfloat16 tile[2][16 * 72];
    __shared__ int2 ewin[2][EWIN];
    int wave = threadIdx.x >> 6, lane = threadIdx.x & 63;
    int nb0 = (blockIdx.x * 2 + wave) * 16;
    if (nb0 >= n) return;
    __hip_bfloat16* T = &tile[wave][0];
    int2* EW = &ewin[wave][0];
    int half = lane >> 5, col = lane & 31;
    const uint* hinu = reinterpret_cast<const uint*>(hin);

    // lanes 0..16 hold the 17 row_ptr boundaries for this wave's nodes
    int bidx = nb0 + (lane < 16 ? lane : 16);
    if (bidx > n) bidx = n;
    int rp = row_ptr[bidx];
    int wave_lo = __shfl(rp, 0);
    int wave_hi = __shfl(rp, 16);
    int cnt = wave_hi - wave_lo;
    bool fast = (cnt <= EWIN);
    if (fast)
        for (int i = lane; i < cnt; i += 64) EW[i] = edges[wave_lo + i];
    // same-wave LDS write->read ordering (in-order LDS pipe; R10-R14 precedent)

    for (int nn = 0; nn < 16; nn++) {
        int node = nb0 + nn;
        float ax = 0.0f, ay = 0.0f;
        if (node < n) {
            if (half == 0) {               // self term counted once
                float dn = dinv[node];
                uint hv = hinu[(size_t)node * 32 + col];
                float dn2 = dn * dn;
                ax = dn2 * __int_as_float(hv << 16);
                ay = dn2 * __int_as_float(hv & 0xffff0000u);
            }
            int lo = __shfl(rp, nn), hi = __shfl(rp, nn + 1);
            if (fast) agg_node<true >(lo, hi, half, col, edges, EW, wave_lo, hinu, ax, ay);
            else      agg_node<false>(lo, hi, half, col, edges, EW, wave_lo, hinu, ax, ay);
        }
        ax += __shfl_xor(ax, 32);
        ay += __shfl_xor(ay, 32);
        if (half == 0) {
            __hip_bfloat16 bx = __float2bfloat16(ax);
            __hip_bfloat16 by = __float2bfloat16(ay);
            uint pack = (uint)(*reinterpret_cast<unsigned short*>(&bx)) |
                        ((uint)(*reinterpret_cast<unsigned short*>(&by)) << 16);
            *reinterpret_cast<uint*>(&T[nn * 72 + 2 * col]) = pack;
        }
    }

    // MFMA phase on the wave's 16x64 tile
    int m = lane & 15, q = lane >> 4;
    short8 a0 = *reinterpret_cast<const short8*>(&T[m * 72 + q * 8]);
    short8 a1 = *reinterpret_cast<const short8*>(&T[m * 72 + 32 + q * 8]);
    int lastn = nb0 + 15 < n ? nb0 + 15 : n - 1;
    bool onegraph = POOL && (nb0 + 15 < n) && (batch[nb0] == batch[lastn]);
    int gA = POOL ? batch[nb0] : 0;
    #pragma unroll
    for (int jt = 0; jt < 4; jt++) {
        short8 bf0 = *reinterpret_cast<const short8*>(Wf + ((size_t)(jt * 2 + 0) * 64 + lane) * 8);
        short8 bf1 = *reinterpret_cast<const short8*>(Wf + ((size_t)(jt * 2 + 1) * 64 + lane) * 8);
        float4v d = {0.0f, 0.0f, 0.0f, 0.0f};
        d = __builtin_amdgcn_mfma_f32_16x16x32_bf16(a0, bf0, d, 0, 0, 0);
        d = __builtin_amdgcn_mfma_f32_16x16x32_bf16(a1, bf1, d, 0, 0, 0);
        float bias = b[jt * 16 + m];           // C/D col = lane&15
        if (POOL) {
            if (onegraph) {
                float s = (d[0] + bias) + (d[1] + bias) + (d[2] + bias) + (d[3] + bias);
                s += __shfl_xor(s, 16);
                s += __shfl_xor(s, 32);
                if (q == 0) atomicAdd(&sums[gA * 64 + jt * 16 + m], s);
            } else {
                #pragma unroll
                for (int r = 0; r < 4; r++) {
                    int node = nb0 + q * 4 + r;
                    if (node < n)
                        atomicAdd(&sums[batch[node] * 64 + jt * 16 + m], d[r] + bias);
                }
            }
        } else {
            #pragma unroll
            for (int r = 0; r < 4; r++) {
                int node = nb0 + q * 4 + r;    // C/D row = quad*4 + reg
                if (node < n) {
                    float v = d[r] + bias;
                    if (RELU) v = fmaxf(v, 0.0f);
                    hout[(size_t)node * 64 + jt * 16 + m] = __float2bfloat16(v);
                }
            }
        }
    }
}

// ---------- pack W (64x64 fp32) into MFMA B-fragment order, bf16 ----------
__global__ void k_prepW(const float* __restrict__ W2, const float* __restrict__ W3,
                        __hip_bfloat16* __restrict__ Wf2, __hip_bfloat16* __restrict__ Wf3) {
    const float* W = blockIdx.x ? W3 : W2;
    __hip_bfloat16* Wf = blockIdx.x ? Wf3 : Wf2;
    int t = threadIdx.x;           // 0..511
    int c = t >> 6, l = t & 63;
    int jt = c >> 1, half = c & 1, nn = l & 15, q = l >> 4;
    #pragma unroll
    for (int j = 0; j < 8; j++) {
        int k = half * 32 + q * 8 + j;
        Wf[t * 8 + j] = __float2bfloat16(W[k * 64 + jt * 16 + nn]);
    }
}

// ---------- head (counts via binary search on sorted batch) ----------
__device__ inline int lower_bound_i(const int* __restrict__ a, int n, int key) {
    int lo = 0, hi = n;
    while (lo < hi) {
        int mid = (lo + hi) >> 1;
        if (a[mid] < key) lo = mid + 1; else hi = mid;
    }
    return lo;
}

__global__ void k_head(const float* __restrict__ sums, const int* __restrict__ batch,
                       const float* __restrict__ ge, const float* __restrict__ Wl,
                       const float* __restrict__ bl, float* __restrict__ out,
                       int n, int ng) {
    int g = blockIdx.x * blockDim.x + threadIdx.x;
    if (g < ng) {
        int lo = lower_bound_i(batch, n, g);
        int hi = lower_bound_i(batch, n, g + 1);
        float c = fmaxf((float)(hi - lo), 1.0f);
        float z[5];
        for (int cl = 0; cl < 5; cl++) z[cl] = bl[cl];
        for (int k = 0; k < 64; k++) {
            float p = sums[g * 64 + k] / c;
            for (int cl = 0; cl < 5; cl++) z[cl] += p * Wl[k * 5 + cl];
        }
        for (int k = 0; k < 64; k++) {
            float p = ge[g * 64 + k];
            for (int cl = 0; cl < 5; cl++) z[cl] += p * Wl[(64 + k) * 5 + cl];
        }
        float m = z[0];
        for (int cl = 1; cl < 5; cl++) m = fmaxf(m, z[cl]);
        float s = 0.0f;
        for (int cl = 0; cl < 5; cl++) s += expf(z[cl] - m);
        float lse = m + logf(s);
        for (int cl = 0; cl < 5; cl++) out[g * 5 + cl] = z[cl] - lse;
    }
}

#define ALIGN16(x) (((x) + 15) & ~(size_t)15)

extern "C" void kernel_launch(void* const* d_in, const int* in_sizes, int n_in,
                              void* d_out, int out_size, void* d_ws, size_t ws_size,
                              hipStream_t stream) {
    const float* x    = (const float*)d_in[0];
    const int*   ei   = (const int*)d_in[1];
    const int*   batch= (const int*)d_in[2];
    const float* ge   = (const float*)d_in[3];
    const float* W1   = (const float*)d_in[4];
    const float* b1   = (const float*)d_in[5];
    const float* W2   = (const float*)d_in[6];
    const float* b2   = (const float*)d_in[7];
    const float* W3   = (const float*)d_in[8];
    const float* b3   = (const float*)d_in[9];
    const float* Wl   = (const float*)d_in[10];
    const float* bl   = (const float*)d_in[11];
    float* out = (float*)d_out;

    const int N = in_sizes[0] / 2;   // x is [N,2]
    const int E = in_sizes[1] / 2;   // edge_index is [2,E]
    const int* src = ei;
    const int* dst = ei + E;
    const int NBUK = (N + 255) >> 8;             // actual dst buckets (<= NBIN)
    const int nbC  = (E + CHUNKB - 1) / CHUNKB;  // sort chunks

    // ---- workspace layout (segments 16B-aligned) ----
    char* wsb = (char*)d_ws;
    float* dinv   = (float*)wsb;                wsb += ALIGN16((size_t)N * 4);
    __hip_bfloat16* h16 = (__hip_bfloat16*)wsb;  wsb += ALIGN16((size_t)64 * N * 2);  // h1
    __hip_bfloat16* buf2= (__hip_bfloat16*)wsb;  wsb += ALIGN16((size_t)64 * N * 2);  // h2
    float* sums   = (float*)wsb;                wsb += ALIGN16((size_t)NG * 64 * 4);
    __hip_bfloat16* Wf2 = (__hip_bfloat16*)wsb; wsb += ALIGN16((size_t)4096 * 2);
    __hip_bfloat16* Wf3 = (__hip_bfloat16*)wsb; wsb += ALIGN16((size_t)4096 * 2);
    int2*  ebuck  = (int2*)wsb;                 wsb += ALIGN16((size_t)E * 8);
    int2*  csr    = (int2*)wsb;                 wsb += ALIGN16((size_t)E * 8);
    int*   row_ptr= (int*)wsb;                  wsb += ALIGN16((size_t)(N + 1) * 4);
    int*   hist   = (int*)wsb;                  wsb += ALIGN16((size_t)NBIN * nbC * 4);
    int*   bsums  = (int*)wsb;                  wsb += 512 * 4;

    const int BS = 256;
    int gN   = (N + BS - 1) / BS;
    int gF   = (N + 31) / 32;                    // k_aggLin: 2 waves x 16 nodes per block
    int nH   = NBIN * nbC;
    int gH   = (nH + 511) / 512;                 // <= 512 for genscan2

    // ---- CSR build: single-pass bucket sort, all histograms in LDS ----
    hipMemsetAsync(sums, 0, (size_t)NG * 64 * 4, stream);
    k_bin_hist<<<nbC, BS, 0, stream>>>(dst, hist, E, nbC);
    genscan1<<<gH, 512, 0, stream>>>(hist, bsums, nH);
    genscan2<<<1, 512, 0, stream>>>(bsums, gH);
    k_bin_scatter<<<nbC, BS, 0, stream>>>(src, dst, hist, bsums, ebuck, E, nbC);
    k_csrA<<<NBUK, BS, 0, stream>>>(ebuck, hist, bsums, row_ptr, dinv, N, nbC, NBUK, E);
    k_csrB<<<NBUK, BS, 0, stream>>>(ebuck, hist, bsums, row_ptr, dinv, csr, nbC);
    k_prepW<<<2, 512, 0, stream>>>(W2, W3, Wf2, Wf3);

    // ---- layer 1: fused pull + lin1 + relu -> h1 (h16) ----
    k_layer1<<<gN, BS, 0, stream>>>(row_ptr, csr, x, dinv, W1, b1, h16, N);

    // ---- layer 2: fused agg(h1) + lin2 + relu -> h2 (buf2) ----
    k_aggLin<1, 0><<<gF, 128, 0, stream>>>(row_ptr, csr, h16, dinv, Wf2, b2, buf2,
                                           nullptr, nullptr, N);

    // ---- layer 3: fused agg(h2) + lin3 + mean-pool -> sums (no h3 buffer) ----
    k_aggLin<0, 1><<<gF, 128, 0, stream>>>(row_ptr, csr, buf2, dinv, Wf3, b3, nullptr,
                                           batch, sums, N);

    // ---- head ----
    k_head<<<1, 128, 0, stream>>>(sums, batch, ge, Wl, bl, out, N, NG);
}